// Round 1
// baseline (471.258 us; speedup 1.0000x reference)
//
#include <hip/hip_runtime.h>

#define Bb 32
#define Nn 512
#define Cc 768
#define Hh 12
#define HDd 64
#define BND 358
#define SCL 0.125f

typedef unsigned short u16;
typedef unsigned int u32;
typedef __attribute__((ext_vector_type(8))) short bf16x8;
typedef __attribute__((ext_vector_type(4))) float f32x4;
typedef __attribute__((ext_vector_type(4))) int i32x4;

__device__ __forceinline__ f32x4 MFMA16(bf16x8 a, bf16x8 b, f32x4 c) {
  return __builtin_amdgcn_mfma_f32_16x16x32_bf16(a, b, c, 0, 0, 0);
}

__device__ __forceinline__ u32 f2bf(float f) {
  u32 u = __builtin_bit_cast(u32, f);
  return (u + 0x7fffu + ((u >> 16) & 1u)) >> 16;
}
__device__ __forceinline__ u32 packbf2(float a, float b) { return f2bf(a) | (f2bf(b) << 16); }
__device__ __forceinline__ float bf2f(u16 h) { return __builtin_bit_cast(float, (u32)h << 16); }

__device__ __forceinline__ void async_copy16(void* lds, const void* g) {
  __builtin_amdgcn_global_load_lds((const __attribute__((address_space(1))) void*)g,
                                   (__attribute__((address_space(3))) void*)lds, 16, 0, 0);
}

// ---------------- elementwise conversions ----------------

__global__ __launch_bounds__(256) void k_convx(const float* __restrict__ x, u16* __restrict__ xb) {
  int gid = blockIdx.x * 256 + threadIdx.x;
  if (gid >= (Bb * Nn * Cc) / 4) return;
  float4 v = *(const float4*)&x[gid * 4];
  u32 p0 = packbf2(v.x, v.y), p1 = packbf2(v.z, v.w);
  uint2 st = {p0, p1};
  *(uint2*)&xb[gid * 4] = st;
}

// src: R x Ccols fp32 row-major; dst: Ccols x R bf16 row-major (transpose+convert)
__global__ __launch_bounds__(256) void k_transpose(const float* __restrict__ src, u16* __restrict__ dst,
                                                   int R, int Ccols) {
  __shared__ float tbuf[32][33];
  int c0 = blockIdx.x * 32, r0 = blockIdx.y * 32;
  int lx = threadIdx.x & 31, ly = threadIdx.x >> 5;  // 32 x 8
  #pragma unroll
  for (int rr = ly; rr < 32; rr += 8) tbuf[rr][lx] = src[(long)(r0 + rr) * Ccols + c0 + lx];
  __syncthreads();
  #pragma unroll
  for (int cc = ly; cc < 32; cc += 8) dst[(long)(c0 + cc) * R + r0 + lx] = (u16)f2bf(tbuf[lx][cc]);
}

__global__ __launch_bounds__(256) void k_lens(const int* __restrict__ mask, int* __restrict__ lens) {
  int b = blockIdx.x, t = threadIdx.x;
  __shared__ int red[256];
  red[t] = mask[(long)b * Nn * Nn + t] + mask[(long)b * Nn * Nn + t + 256];
  __syncthreads();
  for (int s = 128; s > 0; s >>= 1) {
    if (t < s) red[t] += red[t + s];
    __syncthreads();
  }
  if (t == 0) lens[b] = red[0];
}

// ---------------- GEMM: C[m,n] = sum_k A[m,k] * Bt[n,k] ----------------
// A: M x 768 bf16 row-major. Bt: NC x 768 bf16 row-major.
// MODE 0: NC=2304, scatter into Q/K (B,H,N,HD) and Vt (B,H,HD,N), bf16.
// MODE 1: NC=768, store fp32 out[m*768+n] + bias[n].
template <int MODE>
__global__ __launch_bounds__(256) void k_gemm(const u16* __restrict__ A, const u16* __restrict__ Bt,
                                              u16* __restrict__ Qo, u16* __restrict__ Ko,
                                              u16* __restrict__ Vto, float* __restrict__ Co,
                                              const float* __restrict__ bias) {
  constexpr int NC = (MODE == 0) ? 2304 : 768;
  __shared__ u16 As[128 * 32];
  __shared__ u16 Bs[128 * 32];
  int m0 = blockIdx.x * 128, n0 = blockIdx.y * 128;
  int t = threadIdx.x, lane = t & 63, wave = t >> 6;
  int wr = wave >> 1, wc = wave & 1;
  int qlane = lane & 15, g = lane >> 4;
  f32x4 acc[4][4] = {};

  for (int kt = 0; kt < 768 / 32; ++kt) {
    #pragma unroll
    for (int i = 0; i < 2; ++i) {
      int idx = i * 256 + t;              // 512 chunks of 8 elems (16B)
      int row = idx >> 2, col8 = (idx & 3) * 8;
      const u16* ga = A + (long)(m0 + row) * 768 + kt * 32 + col8;
      const u16* gb = Bt + (long)(n0 + row) * 768 + kt * 32 + col8;
      // LDS dest: wave-uniform base; HW adds lane*16 bytes
      async_copy16(&As[(i * 256 + wave * 64) * 8], ga);
      async_copy16(&Bs[(i * 256 + wave * 64) * 8], gb);
    }
    __syncthreads();
    bf16x8 af[4], bf[4];
    #pragma unroll
    for (int xx = 0; xx < 4; ++xx) {
      af[xx] = *(const bf16x8*)&As[(wr * 64 + xx * 16 + qlane) * 32 + g * 8];
      bf[xx] = *(const bf16x8*)&Bs[(wc * 64 + xx * 16 + qlane) * 32 + g * 8];
    }
    #pragma unroll
    for (int mi = 0; mi < 4; ++mi)
      #pragma unroll
      for (int ni = 0; ni < 4; ++ni) acc[mi][ni] = MFMA16(af[mi], bf[ni], acc[mi][ni]);
    __syncthreads();
  }

  #pragma unroll
  for (int mi = 0; mi < 4; ++mi) {
    #pragma unroll
    for (int ni = 0; ni < 4; ++ni) {
      #pragma unroll
      for (int r = 0; r < 4; ++r) {
        int m = m0 + wr * 64 + mi * 16 + g * 4 + r;   // C/D: row=(lane>>4)*4+r
        int n = n0 + wc * 64 + ni * 16 + qlane;       // C/D: col=lane&15
        float v = acc[mi][ni][r];
        if (MODE == 0) {
          int b = m >> 9, qi = m & 511;
          int which = n / Cc, rem = n % Cc;
          int hh = rem >> 6, d = rem & 63;
          u16 hv = (u16)f2bf(v);
          if (which == 0)
            Qo[((long)(b * Hh + hh) * Nn + qi) * HDd + d] = hv;
          else if (which == 1)
            Ko[((long)(b * Hh + hh) * Nn + qi) * HDd + d] = hv;
          else
            Vto[((long)(b * Hh + hh) * HDd + d) * Nn + qi] = hv;
        } else {
          Co[(long)m * Cc + n] = v + bias[n];
        }
      }
    }
  }
}

// ---------------- fused attention ----------------
// One wave = 16 queries, all 512 keys. S^T = mfma(K, Q) so each lane owns
// query q0+(lane&15) and keys (lane>>4)*4+r+16*kt. Softmax in-lane + 2 shfl_xor.
// PV: out^T = mfma(Vt_tile, P^T) with P redistributed via shuffles.
__global__ __launch_bounds__(256) void k_attn(const u16* __restrict__ Q, const u16* __restrict__ K,
                                              const u16* __restrict__ Vt, const int* __restrict__ lens,
                                              u16* __restrict__ AO) {
  int wave = threadIdx.x >> 6, lane = threadIdx.x & 63;
  int bid = blockIdx.x;
  int qt = bid & 7, h = (bid >> 3) % Hh, b = bid / (8 * Hh);
  int q0 = qt * 64 + wave * 16;
  int qlane = lane & 15, g = lane >> 4;
  int len = lens[b];

  const u16* Qb = Q + (long)(b * Hh + h) * Nn * HDd;
  const u16* Kb = K + (long)(b * Hh + h) * Nn * HDd;
  const u16* Vb = Vt + (long)(b * Hh + h) * HDd * Nn;

  bf16x8 qf0 = *(const bf16x8*)(Qb + (q0 + qlane) * HDd + g * 8);
  bf16x8 qf1 = *(const bf16x8*)(Qb + (q0 + qlane) * HDd + 32 + g * 8);

  f32x4 s[32];
  #pragma unroll
  for (int kt = 0; kt < 32; ++kt) {
    const u16* kp = Kb + (kt * 16 + qlane) * HDd + g * 8;
    bf16x8 kf0 = *(const bf16x8*)(kp);
    bf16x8 kf1 = *(const bf16x8*)(kp + 32);
    f32x4 a = {0.f, 0.f, 0.f, 0.f};
    a = MFMA16(kf0, qf0, a);
    a = MFMA16(kf1, qf1, a);
    s[kt] = a;
  }

  float m = -1e30f;
  #pragma unroll
  for (int kt = 0; kt < 32; ++kt) {
    #pragma unroll
    for (int r = 0; r < 4; ++r) {
      int key = kt * 16 + g * 4 + r;
      float v = (key < len) ? s[kt][r] * SCL : -1e9f;
      s[kt][r] = v;
      m = fmaxf(m, v);
    }
  }
  m = fmaxf(m, __shfl_xor(m, 16));
  m = fmaxf(m, __shfl_xor(m, 32));

  float lsum = 0.f;
  u32 pk[32][2];
  #pragma unroll
  for (int kt = 0; kt < 32; ++kt) {
    float p0 = __expf(s[kt][0] - m), p1 = __expf(s[kt][1] - m);
    float p2 = __expf(s[kt][2] - m), p3 = __expf(s[kt][3] - m);
    lsum += (p0 + p1) + (p2 + p3);
    pk[kt][0] = packbf2(p0, p1);
    pk[kt][1] = packbf2(p2, p3);
  }
  lsum += __shfl_xor(lsum, 16);
  lsum += __shfl_xor(lsum, 32);

  f32x4 o[4] = {};
  int srcA = qlane | ((2 * (g & 1)) << 4);
  int srcB = srcA | 16;
  bool hi = (g >> 1) != 0;
  #pragma unroll
  for (int c2 = 0; c2 < 16; ++c2) {
    u32 a0 = (u32)__shfl((int)pk[2 * c2][0], srcA), b0 = (u32)__shfl((int)pk[2 * c2 + 1][0], srcA);
    u32 a1 = (u32)__shfl((int)pk[2 * c2][1], srcA), b1 = (u32)__shfl((int)pk[2 * c2 + 1][1], srcA);
    u32 a2 = (u32)__shfl((int)pk[2 * c2][0], srcB), b2 = (u32)__shfl((int)pk[2 * c2 + 1][0], srcB);
    u32 a3 = (u32)__shfl((int)pk[2 * c2][1], srcB), b3 = (u32)__shfl((int)pk[2 * c2 + 1][1], srcB);
    i32x4 w;
    w.x = (int)(hi ? b0 : a0);
    w.y = (int)(hi ? b1 : a1);
    w.z = (int)(hi ? b2 : a2);
    w.w = (int)(hi ? b3 : a3);
    bf16x8 pf = __builtin_bit_cast(bf16x8, w);
    #pragma unroll
    for (int dt = 0; dt < 4; ++dt) {
      bf16x8 vf = *(const bf16x8*)(Vb + (dt * 16 + qlane) * Nn + c2 * 32 + g * 8);
      o[dt] = MFMA16(vf, pf, o[dt]);
    }
  }

  float inv = 1.f / lsum;
  u16* outp = AO + ((long)(b * Nn + q0 + qlane) * Cc) + h * HDd;
  #pragma unroll
  for (int dt = 0; dt < 4; ++dt) {
    u32 lo = packbf2(o[dt][0] * inv, o[dt][1] * inv);
    u32 hi2 = packbf2(o[dt][2] * inv, o[dt][3] * inv);
    uint2 st = {lo, hi2};
    *(uint2*)(outp + dt * 16 + g * 4) = st;
  }
}

// ---------------- CLS-row scores ----------------
__global__ __launch_bounds__(256) void k_cls(const u16* __restrict__ Q, const u16* __restrict__ K,
                                             const int* __restrict__ lens, float* __restrict__ scores) {
  int b = blockIdx.x, t = threadIdx.x;
  int len = lens[b];
  __shared__ float qrow[64];
  __shared__ float red[256];
  float acc0 = 0.f, acc1 = 0.f;
  for (int h = 0; h < Hh; ++h) {
    const u16* Qb = Q + (long)(b * Hh + h) * Nn * HDd;
    const u16* Kb = K + (long)(b * Hh + h) * Nn * HDd;
    if (t < 64) qrow[t] = bf2f(Qb[t]);
    __syncthreads();
    const bf16x8* kr0 = (const bf16x8*)(Kb + t * HDd);
    const bf16x8* kr1 = (const bf16x8*)(Kb + (t + 256) * HDd);
    float d0 = 0.f, d1 = 0.f;
    #pragma unroll
    for (int c8 = 0; c8 < 8; ++c8) {
      bf16x8 kv0 = kr0[c8], kv1 = kr1[c8];
      #pragma unroll
      for (int j = 0; j < 8; ++j) {
        float qv = qrow[c8 * 8 + j];
        d0 += qv * bf2f((u16)kv0[j]);
        d1 += qv * bf2f((u16)kv1[j]);
      }
    }
    float l0 = (t < len) ? d0 * SCL : -1e9f;
    float l1 = (t + 256 < len) ? d1 * SCL : -1e9f;
    red[t] = fmaxf(l0, l1);
    __syncthreads();
    for (int ss = 128; ss > 0; ss >>= 1) {
      if (t < ss) red[t] = fmaxf(red[t], red[t + ss]);
      __syncthreads();
    }
    float mx = red[0];
    __syncthreads();
    float e0 = __expf(l0 - mx), e1 = __expf(l1 - mx);
    red[t] = e0 + e1;
    __syncthreads();
    for (int ss = 128; ss > 0; ss >>= 1) {
      if (t < ss) red[t] += red[t + ss];
      __syncthreads();
    }
    float invs = 1.f / red[0];
    __syncthreads();
    acc0 += e0 * invs;
    acc1 += e1 * invs;
  }
  float ninf = -__builtin_inff();
  if (t >= 1) scores[b * 511 + (t - 1)] = (t < len) ? acc0 / 12.f : ninf;
  scores[b * 511 + (t + 255)] = (t + 256 < len) ? acc1 / 12.f : ninf;
}

// ---------------- top-k (bitonic sort 512, desc score / asc idx) ----------------
__device__ __forceinline__ bool sless(float sa, int ia, float sb, int ib) {
  return (sa > sb) || (sa == sb && ia < ib);
}

__global__ __launch_bounds__(256) void k_topk(const float* __restrict__ scores,
                                              const int* __restrict__ lens, float* __restrict__ dout) {
  int b = blockIdx.x, t = threadIdx.x;
  __shared__ float sc[512];
  __shared__ int id[512];
  float ninf = -__builtin_inff();
  for (int i = t; i < 512; i += 256) {
    sc[i] = (i < 511) ? scores[b * 511 + i] : ninf;
    id[i] = i;
  }
  for (int k = 2; k <= 512; k <<= 1) {
    for (int j = k >> 1; j > 0; j >>= 1) {
      __syncthreads();
      for (int i = t; i < 512; i += 256) {
        int ixj = i ^ j;
        if (ixj > i) {
          float si = sc[i], sj = sc[ixj];
          int ii = id[i], ij = id[ixj];
          bool up = ((i & k) == 0);
          bool dosw = up ? sless(sj, ij, si, ii) : sless(si, ii, sj, ij);
          if (dosw) {
            sc[i] = sj; sc[ixj] = si;
            id[i] = ij; id[ixj] = ii;
          }
        }
      }
    }
  }
  __syncthreads();
  int len = lens[b];
  int left = (int)ceilf((float)(len - 1) * 0.7f);
  const long OFF_IDX = (long)Bb * Nn * Cc + (long)Bb * BND * Cc;
  for (int p = t; p < BND; p += 256) {
    dout[OFF_IDX + (long)b * BND + p] = (p < left) ? (float)id[p] : 1e9f;
  }
  if (b == 0 && t == 0) dout[OFF_IDX + (long)Bb * BND] = (float)BND;
}

__global__ __launch_bounds__(256) void k_bcast(float* __restrict__ dout) {
  long gid = (long)blockIdx.x * 256 + threadIdx.x;
  const long total = (long)Bb * BND * (Cc / 4);
  if (gid >= total) return;
  long bp = gid / (Cc / 4);
  int c4 = (int)(gid % (Cc / 4));
  const long OFF_INDEX = (long)Bb * Nn * Cc;
  const long OFF_IDX = OFF_INDEX + (long)Bb * BND * Cc;
  float v = dout[OFF_IDX + bp];
  float4 f = {v, v, v, v};
  *(float4*)&dout[OFF_INDEX + bp * Cc + (long)c4 * 4] = f;
}

// ---------------- launch ----------------
extern "C" void kernel_launch(void* const* d_in, const int* in_sizes, int n_in,
                              void* d_out, int out_size, void* d_ws, size_t ws_size,
                              hipStream_t stream) {
  const float* x = (const float*)d_in[0];
  const int* mask = (const int*)d_in[1];
  const float* wqkv = (const float*)d_in[2];
  const float* wproj = (const float*)d_in[3];
  const float* bproj = (const float*)d_in[4];
  float* out = (float*)d_out;

  char* ws = (char*)d_ws;
  u16* Qw  = (u16*)(ws);                    // 25165824 B
  u16* Kw  = (u16*)(ws + 25165824L);        // 25165824 B
  u16* Vtw = (u16*)(ws + 50331648L);        // 25165824 B
  u16* XB  = (u16*)(ws + 75497472L);        // 25165824 B (x bf16; reused as attn out)
  u16* AO  = XB;
  u16* WQT = (u16*)(ws + 100663296L);       // 3538944 B
  u16* WPT = (u16*)(ws + 104202240L);       // 1179648 B
  float* SCO = (float*)(ws + 105381888L);   // 65536 B
  int* LEN = (int*)(ws + 105447424L);       // 128 B

  k_convx<<<12288, 256, 0, stream>>>(x, XB);
  k_transpose<<<dim3(72, 24), 256, 0, stream>>>(wqkv, WQT, 768, 2304);
  k_transpose<<<dim3(24, 24), 256, 0, stream>>>(wproj, WPT, 768, 768);
  k_lens<<<32, 256, 0, stream>>>(mask, LEN);
  k_gemm<0><<<dim3(128, 18), 256, 0, stream>>>(XB, WQT, Qw, Kw, Vtw, nullptr, nullptr);
  k_attn<<<3072, 256, 0, stream>>>(Qw, Kw, Vtw, LEN, AO);
  k_gemm<1><<<dim3(128, 6), 256, 0, stream>>>(AO, WPT, nullptr, nullptr, nullptr, out, bproj);
  k_cls<<<32, 256, 0, stream>>>(Qw, Kw, LEN, SCO);
  k_topk<<<32, 256, 0, stream>>>(SCO, LEN, out);
  k_bcast<<<8592, 256, 0, stream>>>(out);
}

// Round 2
// 386.817 us; speedup vs baseline: 1.2183x; 1.2183x over previous
//
#include <hip/hip_runtime.h>

#define Bb 32
#define Nn 512
#define Cc 768
#define Hh 12
#define HDd 64
#define BND 358
#define SCL 0.125f

typedef unsigned short u16;
typedef unsigned int u32;
typedef __attribute__((ext_vector_type(8))) short bf16x8;
typedef __attribute__((ext_vector_type(4))) float f32x4;
typedef __attribute__((ext_vector_type(4))) int i32x4;

__device__ __forceinline__ f32x4 MFMA16(bf16x8 a, bf16x8 b, f32x4 c) {
  return __builtin_amdgcn_mfma_f32_16x16x32_bf16(a, b, c, 0, 0, 0);
}

__device__ __forceinline__ u32 f2bf(float f) {
  u32 u = __builtin_bit_cast(u32, f);
  return (u + 0x7fffu + ((u >> 16) & 1u)) >> 16;
}
__device__ __forceinline__ u32 packbf2(float a, float b) { return f2bf(a) | (f2bf(b) << 16); }
__device__ __forceinline__ float bf2f(u16 h) { return __builtin_bit_cast(float, (u32)h << 16); }

__device__ __forceinline__ void async_copy16(void* lds, const void* g) {
  __builtin_amdgcn_global_load_lds((const __attribute__((address_space(1))) void*)g,
                                   (__attribute__((address_space(3))) void*)lds, 16, 0, 0);
}

// ---------------- elementwise conversions ----------------

__global__ __launch_bounds__(256) void k_convx(const float* __restrict__ x, u16* __restrict__ xb) {
  int gid = blockIdx.x * 256 + threadIdx.x;
  if (gid >= (Bb * Nn * Cc) / 4) return;
  float4 v = *(const float4*)&x[gid * 4];
  u32 p0 = packbf2(v.x, v.y), p1 = packbf2(v.z, v.w);
  uint2 st = {p0, p1};
  *(uint2*)&xb[gid * 4] = st;
}

// src: R x Ccols fp32 row-major; dst: Ccols x R bf16 row-major (transpose+convert)
__global__ __launch_bounds__(256) void k_transpose(const float* __restrict__ src, u16* __restrict__ dst,
                                                   int R, int Ccols) {
  __shared__ float tbuf[32][33];
  int c0 = blockIdx.x * 32, r0 = blockIdx.y * 32;
  int lx = threadIdx.x & 31, ly = threadIdx.x >> 5;  // 32 x 8
  #pragma unroll
  for (int rr = ly; rr < 32; rr += 8) tbuf[rr][lx] = src[(long)(r0 + rr) * Ccols + c0 + lx];
  __syncthreads();
  #pragma unroll
  for (int cc = ly; cc < 32; cc += 8) dst[(long)(c0 + cc) * R + r0 + lx] = (u16)f2bf(tbuf[lx][cc]);
}

__global__ __launch_bounds__(256) void k_lens(const int* __restrict__ mask, int* __restrict__ lens) {
  int b = blockIdx.x, t = threadIdx.x;
  __shared__ int red[256];
  red[t] = mask[(long)b * Nn * Nn + t] + mask[(long)b * Nn * Nn + t + 256];
  __syncthreads();
  for (int s = 128; s > 0; s >>= 1) {
    if (t < s) red[t] += red[t + s];
    __syncthreads();
  }
  if (t == 0) lens[b] = red[0];
}

// ---------------- GEMM: C[m,n] = sum_k A[m,k] * Bt[n,k] ----------------
template <int MODE>
__global__ __launch_bounds__(256) void k_gemm(const u16* __restrict__ A, const u16* __restrict__ Bt,
                                              u16* __restrict__ Qo, u16* __restrict__ Ko,
                                              u16* __restrict__ Vto, float* __restrict__ Co,
                                              const float* __restrict__ bias) {
  __shared__ u16 As[128 * 32];
  __shared__ u16 Bs[128 * 32];
  int m0 = blockIdx.x * 128, n0 = blockIdx.y * 128;
  int t = threadIdx.x, lane = t & 63, wave = t >> 6;
  int wr = wave >> 1, wc = wave & 1;
  int qlane = lane & 15, g = lane >> 4;
  f32x4 acc[4][4] = {};

  for (int kt = 0; kt < 768 / 32; ++kt) {
    #pragma unroll
    for (int i = 0; i < 2; ++i) {
      int idx = i * 256 + t;              // 512 chunks of 8 elems (16B)
      int row = idx >> 2, col8 = (idx & 3) * 8;
      const u16* ga = A + (long)(m0 + row) * 768 + kt * 32 + col8;
      const u16* gb = Bt + (long)(n0 + row) * 768 + kt * 32 + col8;
      async_copy16(&As[(i * 256 + wave * 64) * 8], ga);
      async_copy16(&Bs[(i * 256 + wave * 64) * 8], gb);
    }
    __syncthreads();
    bf16x8 af[4], bf[4];
    #pragma unroll
    for (int xx = 0; xx < 4; ++xx) {
      af[xx] = *(const bf16x8*)&As[(wr * 64 + xx * 16 + qlane) * 32 + g * 8];
      bf[xx] = *(const bf16x8*)&Bs[(wc * 64 + xx * 16 + qlane) * 32 + g * 8];
    }
    #pragma unroll
    for (int mi = 0; mi < 4; ++mi)
      #pragma unroll
      for (int ni = 0; ni < 4; ++ni) acc[mi][ni] = MFMA16(af[mi], bf[ni], acc[mi][ni]);
    __syncthreads();
  }

  #pragma unroll
  for (int mi = 0; mi < 4; ++mi) {
    #pragma unroll
    for (int ni = 0; ni < 4; ++ni) {
      #pragma unroll
      for (int r = 0; r < 4; ++r) {
        int m = m0 + wr * 64 + mi * 16 + g * 4 + r;
        int n = n0 + wc * 64 + ni * 16 + qlane;
        float v = acc[mi][ni][r];
        if (MODE == 0) {
          int b = m >> 9, qi = m & 511;
          int which = n / Cc, rem = n % Cc;
          int hh = rem >> 6, d = rem & 63;
          u16 hv = (u16)f2bf(v);
          if (which == 0)
            Qo[((long)(b * Hh + hh) * Nn + qi) * HDd + d] = hv;
          else if (which == 1)
            Ko[((long)(b * Hh + hh) * Nn + qi) * HDd + d] = hv;
          else
            Vto[((long)(b * Hh + hh) * HDd + d) * Nn + qi] = hv;
        } else {
          Co[(long)m * Cc + n] = v + bias[n];
        }
      }
    }
  }
}

// ---------------- fused attention (chunked online softmax) ----------------
// Wave = 16 queries. Keys processed in 8 chunks of 64 with online softmax +
// defer-max (THR=8). S^T = mfma(K,Q): lane(qlane,g) owns query qlane, keys
// kt*16+g*4+r. PV: o^T = mfma(Vt, P^T), P redistributed via 8 shfl / 32 keys.
__global__ __launch_bounds__(256) void k_attn(const u16* __restrict__ Q, const u16* __restrict__ K,
                                              const u16* __restrict__ Vt, const int* __restrict__ lens,
                                              u16* __restrict__ AO) {
  int wave = threadIdx.x >> 6, lane = threadIdx.x & 63;
  int bid = blockIdx.x;
  int qt = bid & 7, h = (bid >> 3) % Hh, b = bid / (8 * Hh);
  int q0 = qt * 64 + wave * 16;
  int qlane = lane & 15, g = lane >> 4;
  int len = lens[b];

  const u16* Qb = Q + (long)(b * Hh + h) * Nn * HDd;
  const u16* Kb = K + (long)(b * Hh + h) * Nn * HDd;
  const u16* Vb = Vt + (long)(b * Hh + h) * HDd * Nn;

  bf16x8 qf0 = *(const bf16x8*)(Qb + (q0 + qlane) * HDd + g * 8);
  bf16x8 qf1 = *(const bf16x8*)(Qb + (q0 + qlane) * HDd + 32 + g * 8);

  f32x4 o[4] = {};
  float m = -1e30f, lsum = 0.f;
  int srcA = qlane | ((2 * (g & 1)) << 4);
  int srcB = srcA | 16;
  bool hi = (g >> 1) != 0;

  #pragma unroll 1
  for (int c = 0; c < 8; ++c) {
    f32x4 s[4];
    #pragma unroll
    for (int kt = 0; kt < 4; ++kt) {
      const u16* kp = Kb + ((c * 4 + kt) * 16 + qlane) * HDd + g * 8;
      bf16x8 kf0 = *(const bf16x8*)(kp);
      bf16x8 kf1 = *(const bf16x8*)(kp + 32);
      f32x4 a = {0.f, 0.f, 0.f, 0.f};
      a = MFMA16(kf0, qf0, a);
      a = MFMA16(kf1, qf1, a);
      s[kt] = a;
    }
    float pm = -1e30f;
    #pragma unroll
    for (int kt = 0; kt < 4; ++kt) {
      #pragma unroll
      for (int r = 0; r < 4; ++r) {
        int key = c * 64 + kt * 16 + g * 4 + r;
        float v = (key < len) ? s[kt][r] * SCL : -1e9f;
        s[kt][r] = v;
        pm = fmaxf(pm, v);
      }
    }
    pm = fmaxf(pm, __shfl_xor(pm, 16));
    pm = fmaxf(pm, __shfl_xor(pm, 32));
    if (!__all(pm <= m + 8.f)) {  // defer-max: rescale only on significant growth
      float mn = fmaxf(m, pm);
      float sc = __expf(m - mn);
      lsum *= sc;
      #pragma unroll
      for (int dt = 0; dt < 4; ++dt) {
        o[dt][0] *= sc; o[dt][1] *= sc; o[dt][2] *= sc; o[dt][3] *= sc;
      }
      m = mn;
    }
    u32 pk[4][2];
    #pragma unroll
    for (int kt = 0; kt < 4; ++kt) {
      float p0 = __expf(s[kt][0] - m), p1 = __expf(s[kt][1] - m);
      float p2 = __expf(s[kt][2] - m), p3 = __expf(s[kt][3] - m);
      lsum += (p0 + p1) + (p2 + p3);
      pk[kt][0] = packbf2(p0, p1);
      pk[kt][1] = packbf2(p2, p3);
    }
    #pragma unroll
    for (int c2 = 0; c2 < 2; ++c2) {
      u32 a0 = (u32)__shfl((int)pk[2 * c2][0], srcA), b0 = (u32)__shfl((int)pk[2 * c2 + 1][0], srcA);
      u32 a1 = (u32)__shfl((int)pk[2 * c2][1], srcA), b1 = (u32)__shfl((int)pk[2 * c2 + 1][1], srcA);
      u32 a2 = (u32)__shfl((int)pk[2 * c2][0], srcB), b2 = (u32)__shfl((int)pk[2 * c2 + 1][0], srcB);
      u32 a3 = (u32)__shfl((int)pk[2 * c2][1], srcB), b3 = (u32)__shfl((int)pk[2 * c2 + 1][1], srcB);
      i32x4 w;
      w.x = (int)(hi ? b0 : a0);
      w.y = (int)(hi ? b1 : a1);
      w.z = (int)(hi ? b2 : a2);
      w.w = (int)(hi ? b3 : a3);
      bf16x8 pf = __builtin_bit_cast(bf16x8, w);
      #pragma unroll
      for (int dt = 0; dt < 4; ++dt) {
        bf16x8 vf = *(const bf16x8*)(Vb + (dt * 16 + qlane) * Nn + c * 64 + c2 * 32 + g * 8);
        o[dt] = MFMA16(vf, pf, o[dt]);
      }
    }
  }

  lsum += __shfl_xor(lsum, 16);
  lsum += __shfl_xor(lsum, 32);
  float inv = 1.f / lsum;
  u16* outp = AO + ((long)(b * Nn + q0 + qlane) * Cc) + h * HDd;
  #pragma unroll
  for (int dt = 0; dt < 4; ++dt) {
    u32 lo = packbf2(o[dt][0] * inv, o[dt][1] * inv);
    u32 hi2 = packbf2(o[dt][2] * inv, o[dt][3] * inv);
    uint2 st = {lo, hi2};
    *(uint2*)(outp + dt * 16 + g * 4) = st;
  }
}

// ---------------- CLS-row scores (one block per (b,h), atomic accumulate) ----------------
__global__ __launch_bounds__(256) void k_sco_init(float* __restrict__ sco) {
  int gid = blockIdx.x * 256 + threadIdx.x;
  if (gid < Bb * 511) sco[gid] = 0.f;
}

__global__ __launch_bounds__(256) void k_cls(const u16* __restrict__ Q, const u16* __restrict__ K,
                                             const int* __restrict__ lens, float* __restrict__ scores) {
  int bh = blockIdx.x;  // 0..383
  int b = bh / Hh;
  int t = threadIdx.x;
  int len = lens[b];
  __shared__ float qrow[64];
  __shared__ float red[256];
  const u16* Qb = Q + (long)bh * Nn * HDd;
  const u16* Kb = K + (long)bh * Nn * HDd;
  if (t < 64) qrow[t] = bf2f(Qb[t]);
  __syncthreads();
  const bf16x8* kr0 = (const bf16x8*)(Kb + t * HDd);
  const bf16x8* kr1 = (const bf16x8*)(Kb + (t + 256) * HDd);
  float d0 = 0.f, d1 = 0.f;
  #pragma unroll
  for (int c8 = 0; c8 < 8; ++c8) {
    bf16x8 kv0 = kr0[c8], kv1 = kr1[c8];
    #pragma unroll
    for (int j = 0; j < 8; ++j) {
      float qv = qrow[c8 * 8 + j];
      d0 += qv * bf2f((u16)kv0[j]);
      d1 += qv * bf2f((u16)kv1[j]);
    }
  }
  float l0 = (t < len) ? d0 * SCL : -1e9f;
  float l1 = (t + 256 < len) ? d1 * SCL : -1e9f;
  red[t] = fmaxf(l0, l1);
  __syncthreads();
  for (int ss = 128; ss > 0; ss >>= 1) {
    if (t < ss) red[t] = fmaxf(red[t], red[t + ss]);
    __syncthreads();
  }
  float mx = red[0];
  __syncthreads();
  float e0 = __expf(l0 - mx), e1 = __expf(l1 - mx);
  red[t] = e0 + e1;
  __syncthreads();
  for (int ss = 128; ss > 0; ss >>= 1) {
    if (t < ss) red[t] += red[t + ss];
    __syncthreads();
  }
  float w = (1.f / 12.f) / red[0];
  if (t >= 1) atomicAdd(&scores[b * 511 + (t - 1)], e0 * w);
  atomicAdd(&scores[b * 511 + (t + 255)], e1 * w);
}

// ---------------- top-k (bitonic sort 512, desc score / asc idx) ----------------
__device__ __forceinline__ bool sless(float sa, int ia, float sb, int ib) {
  return (sa > sb) || (sa == sb && ia < ib);
}

__global__ __launch_bounds__(256) void k_topk(const float* __restrict__ scores,
                                              const int* __restrict__ lens, float* __restrict__ dout) {
  int b = blockIdx.x, t = threadIdx.x;
  __shared__ float sc[512];
  __shared__ int id[512];
  float ninf = -__builtin_inff();
  int len = lens[b];
  for (int i = t; i < 512; i += 256) {
    sc[i] = (i < 511 && (i + 1) < len) ? scores[b * 511 + i] : ninf;
    id[i] = i;
  }
  for (int k = 2; k <= 512; k <<= 1) {
    for (int j = k >> 1; j > 0; j >>= 1) {
      __syncthreads();
      for (int i = t; i < 512; i += 256) {
        int ixj = i ^ j;
        if (ixj > i) {
          float si = sc[i], sj = sc[ixj];
          int ii = id[i], ij = id[ixj];
          bool up = ((i & k) == 0);
          bool dosw = up ? sless(sj, ij, si, ii) : sless(si, ii, sj, ij);
          if (dosw) {
            sc[i] = sj; sc[ixj] = si;
            id[i] = ij; id[ixj] = ii;
          }
        }
      }
    }
  }
  __syncthreads();
  int left = (int)ceilf((float)(len - 1) * 0.7f);
  const long OFF_IDX = (long)Bb * Nn * Cc + (long)Bb * BND * Cc;
  for (int p = t; p < BND; p += 256) {
    dout[OFF_IDX + (long)b * BND + p] = (p < left) ? (float)id[p] : 1e9f;
  }
  if (b == 0 && t == 0) dout[OFF_IDX + (long)Bb * BND] = (float)BND;
}

__global__ __launch_bounds__(256) void k_bcast(float* __restrict__ dout) {
  long gid = (long)blockIdx.x * 256 + threadIdx.x;
  const long total = (long)Bb * BND * (Cc / 4);
  if (gid >= total) return;
  long bp = gid / (Cc / 4);
  int c4 = (int)(gid % (Cc / 4));
  const long OFF_INDEX = (long)Bb * Nn * Cc;
  const long OFF_IDX = OFF_INDEX + (long)Bb * BND * Cc;
  float v = dout[OFF_IDX + bp];
  float4 f = {v, v, v, v};
  *(float4*)&dout[OFF_INDEX + bp * Cc + (long)c4 * 4] = f;
}

// ---------------- launch ----------------
extern "C" void kernel_launch(void* const* d_in, const int* in_sizes, int n_in,
                              void* d_out, int out_size, void* d_ws, size_t ws_size,
                              hipStream_t stream) {
  const float* x = (const float*)d_in[0];
  const int* mask = (const int*)d_in[1];
  const float* wqkv = (const float*)d_in[2];
  const float* wproj = (const float*)d_in[3];
  const float* bproj = (const float*)d_in[4];
  float* out = (float*)d_out;

  char* ws = (char*)d_ws;
  u16* Qw  = (u16*)(ws);                    // 25165824 B
  u16* Kw  = (u16*)(ws + 25165824L);        // 25165824 B
  u16* Vtw = (u16*)(ws + 50331648L);        // 25165824 B
  u16* XB  = (u16*)(ws + 75497472L);        // 25165824 B (x bf16; reused as attn out)
  u16* AO  = XB;
  u16* WQT = (u16*)(ws + 100663296L);       // 3538944 B
  u16* WPT = (u16*)(ws + 104202240L);       // 1179648 B
  float* SCO = (float*)(ws + 105381888L);   // 65536 B
  int* LEN = (int*)(ws + 105447424L);       // 128 B

  k_convx<<<12288, 256, 0, stream>>>(x, XB);
  k_transpose<<<dim3(72, 24), 256, 0, stream>>>(wqkv, WQT, 768, 2304);
  k_transpose<<<dim3(24, 24), 256, 0, stream>>>(wproj, WPT, 768, 768);
  k_lens<<<32, 256, 0, stream>>>(mask, LEN);
  k_sco_init<<<64, 256, 0, stream>>>(SCO);
  k_gemm<0><<<dim3(128, 18), 256, 0, stream>>>(XB, WQT, Qw, Kw, Vtw, nullptr, nullptr);
  k_attn<<<3072, 256, 0, stream>>>(Qw, Kw, Vtw, LEN, AO);
  k_gemm<1><<<dim3(128, 6), 256, 0, stream>>>(AO, WPT, nullptr, nullptr, nullptr, out, bproj);
  k_cls<<<384, 256, 0, stream>>>(Qw, Kw, LEN, SCO);
  k_topk<<<32, 256, 0, stream>>>(SCO, LEN, out);
  k_bcast<<<8592, 256, 0, stream>>>(out);
}

// Round 3
// 295.657 us; speedup vs baseline: 1.5939x; 1.3083x over previous
//
#include <hip/hip_runtime.h>

#define Bb 32
#define Nn 512
#define Cc 768
#define Hh 12
#define HDd 64
#define BND 358
#define SCL 0.125f

typedef unsigned short u16;
typedef unsigned int u32;
typedef __attribute__((ext_vector_type(8))) short bf16x8;
typedef __attribute__((ext_vector_type(4))) float f32x4;
typedef __attribute__((ext_vector_type(4))) int i32x4;

__device__ __forceinline__ f32x4 MFMA16(bf16x8 a, bf16x8 b, f32x4 c) {
  return __builtin_amdgcn_mfma_f32_16x16x32_bf16(a, b, c, 0, 0, 0);
}

__device__ __forceinline__ u32 f2bf(float f) {
  u32 u = __builtin_bit_cast(u32, f);
  return (u + 0x7fffu + ((u >> 16) & 1u)) >> 16;
}
__device__ __forceinline__ u32 packbf2(float a, float b) { return f2bf(a) | (f2bf(b) << 16); }
__device__ __forceinline__ float bf2f(u16 h) { return __builtin_bit_cast(float, (u32)h << 16); }

__device__ __forceinline__ void async_copy16(void* lds, const void* g) {
  __builtin_amdgcn_global_load_lds((const __attribute__((address_space(1))) void*)g,
                                   (__attribute__((address_space(3))) void*)lds, 16, 0, 0);
}

// ---------------- elementwise conversions ----------------

__global__ __launch_bounds__(256) void k_convx(const float* __restrict__ x, u16* __restrict__ xb) {
  int gid = blockIdx.x * 256 + threadIdx.x;
  if (gid >= (Bb * Nn * Cc) / 4) return;
  float4 v = *(const float4*)&x[gid * 4];
  u32 p0 = packbf2(v.x, v.y), p1 = packbf2(v.z, v.w);
  uint2 st = {p0, p1};
  *(uint2*)&xb[gid * 4] = st;
}

// src: R x Ccols fp32 row-major; dst: Ccols x R bf16 row-major (transpose+convert)
__global__ __launch_bounds__(256) void k_transpose(const float* __restrict__ src, u16* __restrict__ dst,
                                                   int R, int Ccols) {
  __shared__ float tbuf[32][33];
  int c0 = blockIdx.x * 32, r0 = blockIdx.y * 32;
  int lx = threadIdx.x & 31, ly = threadIdx.x >> 5;  // 32 x 8
  #pragma unroll
  for (int rr = ly; rr < 32; rr += 8) tbuf[rr][lx] = src[(long)(r0 + rr) * Ccols + c0 + lx];
  __syncthreads();
  #pragma unroll
  for (int cc = ly; cc < 32; cc += 8) dst[(long)(c0 + cc) * R + r0 + lx] = (u16)f2bf(tbuf[lx][cc]);
}

__global__ __launch_bounds__(256) void k_lens(const int* __restrict__ mask, int* __restrict__ lens) {
  int b = blockIdx.x, t = threadIdx.x;
  __shared__ int red[256];
  red[t] = mask[(long)b * Nn * Nn + t] + mask[(long)b * Nn * Nn + t + 256];
  __syncthreads();
  for (int s = 128; s > 0; s >>= 1) {
    if (t < s) red[t] += red[t + s];
    __syncthreads();
  }
  if (t == 0) lens[b] = red[0];
}

// ---------------- GEMM: C[m,n] = sum_k A[m,k] * Bt[n,k] ----------------
template <int MODE>
__global__ __launch_bounds__(256) void k_gemm(const u16* __restrict__ A, const u16* __restrict__ Bt,
                                              u16* __restrict__ Qo, u16* __restrict__ Ko,
                                              u16* __restrict__ Vto, float* __restrict__ Co,
                                              const float* __restrict__ bias) {
  __shared__ u16 As[128 * 32];
  __shared__ u16 Bs[128 * 32];
  int m0 = blockIdx.x * 128, n0 = blockIdx.y * 128;
  int t = threadIdx.x, lane = t & 63, wave = t >> 6;
  int wr = wave >> 1, wc = wave & 1;
  int qlane = lane & 15, g = lane >> 4;
  f32x4 acc[4][4] = {};

  for (int kt = 0; kt < 768 / 32; ++kt) {
    #pragma unroll
    for (int i = 0; i < 2; ++i) {
      int idx = i * 256 + t;              // 512 chunks of 8 elems (16B)
      int row = idx >> 2, col8 = (idx & 3) * 8;
      const u16* ga = A + (long)(m0 + row) * 768 + kt * 32 + col8;
      const u16* gb = Bt + (long)(n0 + row) * 768 + kt * 32 + col8;
      async_copy16(&As[(i * 256 + wave * 64) * 8], ga);
      async_copy16(&Bs[(i * 256 + wave * 64) * 8], gb);
    }
    __syncthreads();
    bf16x8 af[4], bf[4];
    #pragma unroll
    for (int xx = 0; xx < 4; ++xx) {
      af[xx] = *(const bf16x8*)&As[(wr * 64 + xx * 16 + qlane) * 32 + g * 8];
      bf[xx] = *(const bf16x8*)&Bs[(wc * 64 + xx * 16 + qlane) * 32 + g * 8];
    }
    #pragma unroll
    for (int mi = 0; mi < 4; ++mi)
      #pragma unroll
      for (int ni = 0; ni < 4; ++ni) acc[mi][ni] = MFMA16(af[mi], bf[ni], acc[mi][ni]);
    __syncthreads();
  }

  #pragma unroll
  for (int mi = 0; mi < 4; ++mi) {
    #pragma unroll
    for (int ni = 0; ni < 4; ++ni) {
      #pragma unroll
      for (int r = 0; r < 4; ++r) {
        int m = m0 + wr * 64 + mi * 16 + g * 4 + r;
        int n = n0 + wc * 64 + ni * 16 + qlane;
        float v = acc[mi][ni][r];
        if (MODE == 0) {
          int b = m >> 9, qi = m & 511;
          int which = n / Cc, rem = n % Cc;
          int hh = rem >> 6, d = rem & 63;
          u16 hv = (u16)f2bf(v);
          if (which == 0)
            Qo[((long)(b * Hh + hh) * Nn + qi) * HDd + d] = hv;
          else if (which == 1)
            Ko[((long)(b * Hh + hh) * Nn + qi) * HDd + d] = hv;
          else
            Vto[((long)(b * Hh + hh) * HDd + d) * Nn + qi] = hv;
        } else {
          Co[(long)m * Cc + n] = v + bias[n];
        }
      }
    }
  }
}

// ---------------- fused attention (4 q-tiles / wave, chunked online softmax) ----------------
// Wave = 64 queries (4 tiles of 16). Keys in 8 chunks of 64. K/V fragments
// loaded ONCE per wave per chunk, shared by 4 independent tile pipelines (ILP).
// S^T = mfma(K,Q): lane(qlane,g) owns query qlane, keys kt*16+g*4+r.
// PV: o^T = mfma(Vt, P^T), P redistributed via 8 shfl per (tile, 32-keys).
__global__ __launch_bounds__(256) void k_attn(const u16* __restrict__ Q, const u16* __restrict__ K,
                                              const u16* __restrict__ Vt, const int* __restrict__ lens,
                                              u16* __restrict__ AO) {
  int wave = threadIdx.x >> 6, lane = threadIdx.x & 63;
  int bid = blockIdx.x;
  int half = bid & 1, h = (bid >> 1) % Hh, b = bid / (2 * Hh);
  int q0w = half * 256 + wave * 64;
  int qlane = lane & 15, g = lane >> 4;
  int len = lens[b];

  const u16* Qb = Q + (long)(b * Hh + h) * Nn * HDd;
  const u16* Kb = K + (long)(b * Hh + h) * Nn * HDd;
  const u16* Vb = Vt + (long)(b * Hh + h) * HDd * Nn;

  bf16x8 qf[4][2];
  #pragma unroll
  for (int t = 0; t < 4; ++t) {
    qf[t][0] = *(const bf16x8*)(Qb + (q0w + t * 16 + qlane) * HDd + g * 8);
    qf[t][1] = *(const bf16x8*)(Qb + (q0w + t * 16 + qlane) * HDd + 32 + g * 8);
  }

  f32x4 o[4][4] = {};
  float m[4] = {-1e30f, -1e30f, -1e30f, -1e30f};
  float l[4] = {0.f, 0.f, 0.f, 0.f};
  int srcA = qlane | ((2 * (g & 1)) << 4);
  int srcB = srcA | 16;
  bool hi = (g >> 1) != 0;

  #pragma unroll 1
  for (int c = 0; c < 8; ++c) {
    // shared K fragments (4 kt x 2 halves of HD) and V fragments (2 c2 x 4 dt)
    bf16x8 kf[4][2], vf[2][4];
    #pragma unroll
    for (int kt = 0; kt < 4; ++kt) {
      const u16* kp = Kb + ((c * 4 + kt) * 16 + qlane) * HDd + g * 8;
      kf[kt][0] = *(const bf16x8*)(kp);
      kf[kt][1] = *(const bf16x8*)(kp + 32);
    }
    #pragma unroll
    for (int c2 = 0; c2 < 2; ++c2)
      #pragma unroll
      for (int dt = 0; dt < 4; ++dt)
        vf[c2][dt] = *(const bf16x8*)(Vb + (dt * 16 + qlane) * Nn + c * 64 + c2 * 32 + g * 8);

    #pragma unroll
    for (int t = 0; t < 4; ++t) {
      f32x4 s[4];
      #pragma unroll
      for (int kt = 0; kt < 4; ++kt) {
        f32x4 a = {0.f, 0.f, 0.f, 0.f};
        a = MFMA16(kf[kt][0], qf[t][0], a);
        a = MFMA16(kf[kt][1], qf[t][1], a);
        s[kt] = a;
      }
      float pm = -1e30f;
      #pragma unroll
      for (int kt = 0; kt < 4; ++kt) {
        #pragma unroll
        for (int r = 0; r < 4; ++r) {
          int key = c * 64 + kt * 16 + g * 4 + r;
          float v = (key < len) ? s[kt][r] * SCL : -1e9f;
          s[kt][r] = v;
          pm = fmaxf(pm, v);
        }
      }
      pm = fmaxf(pm, __shfl_xor(pm, 16));
      pm = fmaxf(pm, __shfl_xor(pm, 32));
      if (!__all(pm <= m[t] + 8.f)) {  // defer-max
        float mn = fmaxf(m[t], pm);
        float sc = __expf(m[t] - mn);
        l[t] *= sc;
        #pragma unroll
        for (int dt = 0; dt < 4; ++dt) {
          o[t][dt][0] *= sc; o[t][dt][1] *= sc; o[t][dt][2] *= sc; o[t][dt][3] *= sc;
        }
        m[t] = mn;
      }
      u32 pk[4][2];
      #pragma unroll
      for (int kt = 0; kt < 4; ++kt) {
        float p0 = __expf(s[kt][0] - m[t]), p1 = __expf(s[kt][1] - m[t]);
        float p2 = __expf(s[kt][2] - m[t]), p3 = __expf(s[kt][3] - m[t]);
        l[t] += (p0 + p1) + (p2 + p3);
        pk[kt][0] = packbf2(p0, p1);
        pk[kt][1] = packbf2(p2, p3);
      }
      #pragma unroll
      for (int c2 = 0; c2 < 2; ++c2) {
        u32 a0 = (u32)__shfl((int)pk[2 * c2][0], srcA), b0 = (u32)__shfl((int)pk[2 * c2 + 1][0], srcA);
        u32 a1 = (u32)__shfl((int)pk[2 * c2][1], srcA), b1 = (u32)__shfl((int)pk[2 * c2 + 1][1], srcA);
        u32 a2 = (u32)__shfl((int)pk[2 * c2][0], srcB), b2 = (u32)__shfl((int)pk[2 * c2 + 1][0], srcB);
        u32 a3 = (u32)__shfl((int)pk[2 * c2][1], srcB), b3 = (u32)__shfl((int)pk[2 * c2 + 1][1], srcB);
        i32x4 w;
        w.x = (int)(hi ? b0 : a0);
        w.y = (int)(hi ? b1 : a1);
        w.z = (int)(hi ? b2 : a2);
        w.w = (int)(hi ? b3 : a3);
        bf16x8 pf = __builtin_bit_cast(bf16x8, w);
        #pragma unroll
        for (int dt = 0; dt < 4; ++dt) o[t][dt] = MFMA16(vf[c2][dt], pf, o[t][dt]);
      }
    }
  }

  #pragma unroll
  for (int t = 0; t < 4; ++t) {
    float ls = l[t];
    ls += __shfl_xor(ls, 16);
    ls += __shfl_xor(ls, 32);
    float inv = 1.f / ls;
    u16* outp = AO + ((long)(b * Nn + q0w + t * 16 + qlane) * Cc) + h * HDd;
    #pragma unroll
    for (int dt = 0; dt < 4; ++dt) {
      u32 lo = packbf2(o[t][dt][0] * inv, o[t][dt][1] * inv);
      u32 hi2 = packbf2(o[t][dt][2] * inv, o[t][dt][3] * inv);
      uint2 st = {lo, hi2};
      *(uint2*)(outp + dt * 16 + g * 4) = st;
    }
  }
}

// ---------------- CLS-row scores (one block per (b,h), atomic accumulate) ----------------
__global__ __launch_bounds__(256) void k_sco_init(float* __restrict__ sco) {
  int gid = blockIdx.x * 256 + threadIdx.x;
  if (gid < Bb * 511) sco[gid] = 0.f;
}

__global__ __launch_bounds__(256) void k_cls(const u16* __restrict__ Q, const u16* __restrict__ K,
                                             const int* __restrict__ lens, float* __restrict__ scores) {
  int bh = blockIdx.x;  // 0..383
  int b = bh / Hh;
  int t = threadIdx.x;
  int len = lens[b];
  __shared__ float qrow[64];
  __shared__ float red[256];
  const u16* Qb = Q + (long)bh * Nn * HDd;
  const u16* Kb = K + (long)bh * Nn * HDd;
  if (t < 64) qrow[t] = bf2f(Qb[t]);
  __syncthreads();
  const bf16x8* kr0 = (const bf16x8*)(Kb + t * HDd);
  const bf16x8* kr1 = (const bf16x8*)(Kb + (t + 256) * HDd);
  float d0 = 0.f, d1 = 0.f;
  #pragma unroll
  for (int c8 = 0; c8 < 8; ++c8) {
    bf16x8 kv0 = kr0[c8], kv1 = kr1[c8];
    #pragma unroll
    for (int j = 0; j < 8; ++j) {
      float qv = qrow[c8 * 8 + j];
      d0 += qv * bf2f((u16)kv0[j]);
      d1 += qv * bf2f((u16)kv1[j]);
    }
  }
  float l0 = (t < len) ? d0 * SCL : -1e9f;
  float l1 = (t + 256 < len) ? d1 * SCL : -1e9f;
  red[t] = fmaxf(l0, l1);
  __syncthreads();
  for (int ss = 128; ss > 0; ss >>= 1) {
    if (t < ss) red[t] = fmaxf(red[t], red[t + ss]);
    __syncthreads();
  }
  float mx = red[0];
  __syncthreads();
  float e0 = __expf(l0 - mx), e1 = __expf(l1 - mx);
  red[t] = e0 + e1;
  __syncthreads();
  for (int ss = 128; ss > 0; ss >>= 1) {
    if (t < ss) red[t] += red[t + ss];
    __syncthreads();
  }
  float w = (1.f / 12.f) / red[0];
  if (t >= 1) atomicAdd(&scores[b * 511 + (t - 1)], e0 * w);
  atomicAdd(&scores[b * 511 + (t + 255)], e1 * w);
}

// ---------------- top-k (bitonic sort 512, desc score / asc idx) ----------------
__device__ __forceinline__ bool sless(float sa, int ia, float sb, int ib) {
  return (sa > sb) || (sa == sb && ia < ib);
}

__global__ __launch_bounds__(256) void k_topk(const float* __restrict__ scores,
                                              const int* __restrict__ lens, float* __restrict__ dout) {
  int b = blockIdx.x, t = threadIdx.x;
  __shared__ float sc[512];
  __shared__ int id[512];
  float ninf = -__builtin_inff();
  int len = lens[b];
  for (int i = t; i < 512; i += 256) {
    sc[i] = (i < 511 && (i + 1) < len) ? scores[b * 511 + i] : ninf;
    id[i] = i;
  }
  for (int k = 2; k <= 512; k <<= 1) {
    for (int j = k >> 1; j > 0; j >>= 1) {
      __syncthreads();
      for (int i = t; i < 512; i += 256) {
        int ixj = i ^ j;
        if (ixj > i) {
          float si = sc[i], sj = sc[ixj];
          int ii = id[i], ij = id[ixj];
          bool up = ((i & k) == 0);
          bool dosw = up ? sless(sj, ij, si, ii) : sless(si, ii, sj, ij);
          if (dosw) {
            sc[i] = sj; sc[ixj] = si;
            id[i] = ij; id[ixj] = ii;
          }
        }
      }
    }
  }
  __syncthreads();
  int left = (int)ceilf((float)(len - 1) * 0.7f);
  const long OFF_IDX = (long)Bb * Nn * Cc + (long)Bb * BND * Cc;
  for (int p = t; p < BND; p += 256) {
    dout[OFF_IDX + (long)b * BND + p] = (p < left) ? (float)id[p] : 1e9f;
  }
  if (b == 0 && t == 0) dout[OFF_IDX + (long)Bb * BND] = (float)BND;
}

__global__ __launch_bounds__(256) void k_bcast(float* __restrict__ dout) {
  long gid = (long)blockIdx.x * 256 + threadIdx.x;
  const long total = (long)Bb * BND * (Cc / 4);
  if (gid >= total) return;
  long bp = gid / (Cc / 4);
  int c4 = (int)(gid % (Cc / 4));
  const long OFF_INDEX = (long)Bb * Nn * Cc;
  const long OFF_IDX = OFF_INDEX + (long)Bb * BND * Cc;
  float v = dout[OFF_IDX + bp];
  float4 f = {v, v, v, v};
  *(float4*)&dout[OFF_INDEX + bp * Cc + (long)c4 * 4] = f;
}

// ---------------- launch ----------------
extern "C" void kernel_launch(void* const* d_in, const int* in_sizes, int n_in,
                              void* d_out, int out_size, void* d_ws, size_t ws_size,
                              hipStream_t stream) {
  const float* x = (const float*)d_in[0];
  const int* mask = (const int*)d_in[1];
  const float* wqkv = (const float*)d_in[2];
  const float* wproj = (const float*)d_in[3];
  const float* bproj = (const float*)d_in[4];
  float* out = (float*)d_out;

  char* ws = (char*)d_ws;
  u16* Qw  = (u16*)(ws);                    // 25165824 B
  u16* Kw  = (u16*)(ws + 25165824L);        // 25165824 B
  u16* Vtw = (u16*)(ws + 50331648L);        // 25165824 B
  u16* XB  = (u16*)(ws + 75497472L);        // 25165824 B (x bf16; reused as attn out)
  u16* AO  = XB;
  u16* WQT = (u16*)(ws + 100663296L);       // 3538944 B
  u16* WPT = (u16*)(ws + 104202240L);       // 1179648 B
  float* SCO = (float*)(ws + 105381888L);   // 65536 B
  int* LEN = (int*)(ws + 105447424L);       // 128 B

  k_convx<<<12288, 256, 0, stream>>>(x, XB);
  k_transpose<<<dim3(72, 24), 256, 0, stream>>>(wqkv, WQT, 768, 2304);
  k_transpose<<<dim3(24, 24), 256, 0, stream>>>(wproj, WPT, 768, 768);
  k_lens<<<32, 256, 0, stream>>>(mask, LEN);
  k_sco_init<<<64, 256, 0, stream>>>(SCO);
  k_gemm<0><<<dim3(128, 18), 256, 0, stream>>>(XB, WQT, Qw, Kw, Vtw, nullptr, nullptr);
  k_attn<<<768, 256, 0, stream>>>(Qw, Kw, Vtw, LEN, AO);
  k_gemm<1><<<dim3(128, 6), 256, 0, stream>>>(AO, WPT, nullptr, nullptr, nullptr, out, bproj);
  k_cls<<<384, 256, 0, stream>>>(Qw, Kw, LEN, SCO);
  k_topk<<<32, 256, 0, stream>>>(SCO, LEN, out);
  k_bcast<<<8592, 256, 0, stream>>>(out);
}

// Round 4
// 253.773 us; speedup vs baseline: 1.8570x; 1.1650x over previous
//
#include <hip/hip_runtime.h>

#define Bb 32
#define Nn 512
#define Cc 768
#define Hh 12
#define HDd 64
#define BND 358
#define SCL 0.125f

typedef unsigned short u16;
typedef unsigned int u32;
typedef __attribute__((ext_vector_type(8))) short bf16x8;
typedef __attribute__((ext_vector_type(4))) float f32x4;
typedef __attribute__((ext_vector_type(4))) int i32x4;

__device__ __forceinline__ f32x4 MFMA16(bf16x8 a, bf16x8 b, f32x4 c) {
  return __builtin_amdgcn_mfma_f32_16x16x32_bf16(a, b, c, 0, 0, 0);
}

__device__ __forceinline__ u32 f2bf(float f) {
  u32 u = __builtin_bit_cast(u32, f);
  return (u + 0x7fffu + ((u >> 16) & 1u)) >> 16;
}
__device__ __forceinline__ u32 packbf2(float a, float b) { return f2bf(a) | (f2bf(b) << 16); }
__device__ __forceinline__ float bf2f(u16 h) { return __builtin_bit_cast(float, (u32)h << 16); }

__device__ __forceinline__ void async_copy16(void* lds, const void* g) {
  __builtin_amdgcn_global_load_lds((const __attribute__((address_space(1))) void*)g,
                                   (__attribute__((address_space(3))) void*)lds, 16, 0, 0);
}

// ---------------- elementwise conversions ----------------

__global__ __launch_bounds__(256) void k_convx(const float* __restrict__ x, u16* __restrict__ xb) {
  int gid = blockIdx.x * 256 + threadIdx.x;
  if (gid >= (Bb * Nn * Cc) / 4) return;
  float4 v = *(const float4*)&x[gid * 4];
  u32 p0 = packbf2(v.x, v.y), p1 = packbf2(v.z, v.w);
  uint2 st = {p0, p1};
  *(uint2*)&xb[gid * 4] = st;
}

// src: R x Ccols fp32 row-major; dst: Ccols x R bf16 row-major (transpose+convert)
__global__ __launch_bounds__(256) void k_transpose(const float* __restrict__ src, u16* __restrict__ dst,
                                                   int R, int Ccols) {
  __shared__ float tbuf[32][33];
  int c0 = blockIdx.x * 32, r0 = blockIdx.y * 32;
  int lx = threadIdx.x & 31, ly = threadIdx.x >> 5;  // 32 x 8
  #pragma unroll
  for (int rr = ly; rr < 32; rr += 8) tbuf[rr][lx] = src[(long)(r0 + rr) * Ccols + c0 + lx];
  __syncthreads();
  #pragma unroll
  for (int cc = ly; cc < 32; cc += 8) dst[(long)(c0 + cc) * R + r0 + lx] = (u16)f2bf(tbuf[lx][cc]);
}

__global__ __launch_bounds__(256) void k_lens(const int* __restrict__ mask, int* __restrict__ lens) {
  int b = blockIdx.x, t = threadIdx.x;
  __shared__ int red[256];
  red[t] = mask[(long)b * Nn * Nn + t] + mask[(long)b * Nn * Nn + t + 256];
  __syncthreads();
  for (int s = 128; s > 0; s >>= 1) {
    if (t < s) red[t] += red[t + s];
    __syncthreads();
  }
  if (t == 0) lens[b] = red[0];
}

// ---------------- GEMM v2: 128x128 tile, BK=64, double-buffered LDS, ----------------
// stage-ahead 2-phase, XOR-swizzled LDS (linear dest + pre-swizzled global src).
// C[m,n] = sum_k A[m,k]*Bt[n,k].  A: Mx768, Bt: NCx768 (both bf16 row-major).
// MODE 0, SWAP 1: Q/K blocks (n in [0,1536)). acc=mfma(bf,af): reg quad spans n
//                 -> 4 consecutive d -> one uint2 store into Q/K (B,H,N,HD).
// MODE 0, SWAP 0: V blocks (n>=1536). reg quad spans m -> 4 consecutive qi ->
//                 one uint2 store into Vt (B,H,HD,N).
// MODE 1, SWAP 0: proj: fp32 out[m*768+n] + bias[n].
template <int MODE, int SWAP>
__global__ __launch_bounds__(256) void k_gemm2(const u16* __restrict__ A, const u16* __restrict__ Bt,
                                               int nb0, u16* __restrict__ Qo, u16* __restrict__ Ko,
                                               u16* __restrict__ Vto, float* __restrict__ Co,
                                               const float* __restrict__ bias) {
  __shared__ u16 As[2][128 * 64];
  __shared__ u16 Bs[2][128 * 64];
  int m0 = blockIdx.x * 128;
  int nb = nb0 + blockIdx.y * 128;
  int t = threadIdx.x, lane = t & 63, wave = t >> 6;
  int wr = wave >> 1, wc = wave & 1;
  int qlane = lane & 15, g = lane >> 4;
  f32x4 acc[4][4] = {};

  // stage one K-tile (128 rows x 128B for each operand); dest linear, source
  // column pre-swizzled so a swizzled READ sees logical data (rule #21).
  auto stage = [&](int kt, int buf) {
    #pragma unroll
    for (int i = 0; i < 4; ++i) {
      int chunk = i * 256 + t;            // 1024 chunks of 16B per operand
      int row = chunk >> 3;
      int cp = (chunk & 7) << 4;          // dest byte-pos within 128B row
      int src = cp ^ ((row & 7) << 4);    // inverse-swizzled source byte-pos
      const u16* ga = A + (long)(m0 + row) * 768 + kt * 64 + (src >> 1);
      const u16* gb = Bt + (long)(nb + row) * 768 + kt * 64 + (src >> 1);
      async_copy16(&As[buf][(i * 256 + wave * 64) * 8], ga);
      async_copy16(&Bs[buf][(i * 256 + wave * 64) * 8], gb);
    }
  };

  auto compute = [&](int buf) {
    #pragma unroll
    for (int kk = 0; kk < 2; ++kk) {
      bf16x8 af[4], bf[4];
      #pragma unroll
      for (int x = 0; x < 4; ++x) {
        int ra = wr * 64 + x * 16 + qlane;
        int ca = (kk * 64 + g * 16) ^ ((ra & 7) << 4);   // swizzled read byte-pos
        af[x] = *(const bf16x8*)&As[buf][ra * 64 + (ca >> 1)];
        int rb = wc * 64 + x * 16 + qlane;
        int cb = (kk * 64 + g * 16) ^ ((rb & 7) << 4);
        bf[x] = *(const bf16x8*)&Bs[buf][rb * 64 + (cb >> 1)];
      }
      #pragma unroll
      for (int mi = 0; mi < 4; ++mi)
        #pragma unroll
        for (int ni = 0; ni < 4; ++ni)
          acc[mi][ni] = SWAP ? MFMA16(bf[ni], af[mi], acc[mi][ni])
                             : MFMA16(af[mi], bf[ni], acc[mi][ni]);
    }
  };

  stage(0, 0);
  __syncthreads();
  int cur = 0;
  for (int kt = 0; kt < 12; ++kt) {
    if (kt < 11) stage(kt + 1, cur ^ 1);  // prefetch flies during compute
    compute(cur);
    __syncthreads();                       // drains vmcnt (stage) + read reuse
    cur ^= 1;
  }

  if (MODE == 0 && SWAP == 1) {
    // D rows (g*4+r) <-> bf = n side; D cols (qlane) <-> af = m side.
    #pragma unroll
    for (int mi = 0; mi < 4; ++mi) {
      int m = m0 + wr * 64 + mi * 16 + qlane;
      int b = m >> 9, qi = m & 511;
      #pragma unroll
      for (int ni = 0; ni < 4; ++ni) {
        int nf = nb + wc * 64 + ni * 16 + g * 4;
        int which = nf >= 768;
        int rem = nf - which * 768;
        int hh = rem >> 6, d0 = rem & 63;
        u16* dst = (which ? Ko : Qo) + ((long)(b * Hh + hh) * Nn + qi) * HDd + d0;
        uint2 st = {packbf2(acc[mi][ni][0], acc[mi][ni][1]),
                    packbf2(acc[mi][ni][2], acc[mi][ni][3])};
        *(uint2*)dst = st;
      }
    }
  } else if (MODE == 0) {
    // V: rows (g*4+r) <-> af = m side (4 consecutive qi); cols (qlane) <-> n.
    #pragma unroll
    for (int mi = 0; mi < 4; ++mi) {
      int m = m0 + wr * 64 + mi * 16 + g * 4;
      int b = m >> 9, qi = m & 511;
      #pragma unroll
      for (int ni = 0; ni < 4; ++ni) {
        int rem = nb + wc * 64 + ni * 16 + qlane - 1536;
        int hh = rem >> 6, d = rem & 63;
        u16* dst = Vto + ((long)(b * Hh + hh) * HDd + d) * Nn + qi;
        uint2 st = {packbf2(acc[mi][ni][0], acc[mi][ni][1]),
                    packbf2(acc[mi][ni][2], acc[mi][ni][3])};
        *(uint2*)dst = st;
      }
    }
  } else {
    #pragma unroll
    for (int mi = 0; mi < 4; ++mi) {
      #pragma unroll
      for (int ni = 0; ni < 4; ++ni) {
        int n = nb + wc * 64 + ni * 16 + qlane;
        float bv = bias[n];
        #pragma unroll
        for (int r = 0; r < 4; ++r) {
          int m = m0 + wr * 64 + mi * 16 + g * 4 + r;
          Co[(long)m * Cc + n] = acc[mi][ni][r] + bv;
        }
      }
    }
  }
}

// ---------------- fused attention (4 q-tiles / wave, chunked online softmax) ----------------
__global__ __launch_bounds__(256) void k_attn(const u16* __restrict__ Q, const u16* __restrict__ K,
                                              const u16* __restrict__ Vt, const int* __restrict__ lens,
                                              u16* __restrict__ AO) {
  int wave = threadIdx.x >> 6, lane = threadIdx.x & 63;
  int bid = blockIdx.x;
  int half = bid & 1, h = (bid >> 1) % Hh, b = bid / (2 * Hh);
  int q0w = half * 256 + wave * 64;
  int qlane = lane & 15, g = lane >> 4;
  int len = lens[b];

  const u16* Qb = Q + (long)(b * Hh + h) * Nn * HDd;
  const u16* Kb = K + (long)(b * Hh + h) * Nn * HDd;
  const u16* Vb = Vt + (long)(b * Hh + h) * HDd * Nn;

  bf16x8 qf[4][2];
  #pragma unroll
  for (int t = 0; t < 4; ++t) {
    qf[t][0] = *(const bf16x8*)(Qb + (q0w + t * 16 + qlane) * HDd + g * 8);
    qf[t][1] = *(const bf16x8*)(Qb + (q0w + t * 16 + qlane) * HDd + 32 + g * 8);
  }

  f32x4 o[4][4] = {};
  float m[4] = {-1e30f, -1e30f, -1e30f, -1e30f};
  float l[4] = {0.f, 0.f, 0.f, 0.f};
  int srcA = qlane | ((2 * (g & 1)) << 4);
  int srcB = srcA | 16;
  bool hi = (g >> 1) != 0;

  #pragma unroll 1
  for (int c = 0; c < 8; ++c) {
    bf16x8 kf[4][2], vf[2][4];
    #pragma unroll
    for (int kt = 0; kt < 4; ++kt) {
      const u16* kp = Kb + ((c * 4 + kt) * 16 + qlane) * HDd + g * 8;
      kf[kt][0] = *(const bf16x8*)(kp);
      kf[kt][1] = *(const bf16x8*)(kp + 32);
    }
    #pragma unroll
    for (int c2 = 0; c2 < 2; ++c2)
      #pragma unroll
      for (int dt = 0; dt < 4; ++dt)
        vf[c2][dt] = *(const bf16x8*)(Vb + (dt * 16 + qlane) * Nn + c * 64 + c2 * 32 + g * 8);

    #pragma unroll
    for (int t = 0; t < 4; ++t) {
      f32x4 s[4];
      #pragma unroll
      for (int kt = 0; kt < 4; ++kt) {
        f32x4 a = {0.f, 0.f, 0.f, 0.f};
        a = MFMA16(kf[kt][0], qf[t][0], a);
        a = MFMA16(kf[kt][1], qf[t][1], a);
        s[kt] = a;
      }
      float pm = -1e30f;
      #pragma unroll
      for (int kt = 0; kt < 4; ++kt) {
        #pragma unroll
        for (int r = 0; r < 4; ++r) {
          int key = c * 64 + kt * 16 + g * 4 + r;
          float v = (key < len) ? s[kt][r] * SCL : -1e9f;
          s[kt][r] = v;
          pm = fmaxf(pm, v);
        }
      }
      pm = fmaxf(pm, __shfl_xor(pm, 16));
      pm = fmaxf(pm, __shfl_xor(pm, 32));
      if (!__all(pm <= m[t] + 8.f)) {  // defer-max
        float mn = fmaxf(m[t], pm);
        float sc = __expf(m[t] - mn);
        l[t] *= sc;
        #pragma unroll
        for (int dt = 0; dt < 4; ++dt) {
          o[t][dt][0] *= sc; o[t][dt][1] *= sc; o[t][dt][2] *= sc; o[t][dt][3] *= sc;
        }
        m[t] = mn;
      }
      u32 pk[4][2];
      #pragma unroll
      for (int kt = 0; kt < 4; ++kt) {
        float p0 = __expf(s[kt][0] - m[t]), p1 = __expf(s[kt][1] - m[t]);
        float p2 = __expf(s[kt][2] - m[t]), p3 = __expf(s[kt][3] - m[t]);
        l[t] += (p0 + p1) + (p2 + p3);
        pk[kt][0] = packbf2(p0, p1);
        pk[kt][1] = packbf2(p2, p3);
      }
      #pragma unroll
      for (int c2 = 0; c2 < 2; ++c2) {
        u32 a0 = (u32)__shfl((int)pk[2 * c2][0], srcA), b0 = (u32)__shfl((int)pk[2 * c2 + 1][0], srcA);
        u32 a1 = (u32)__shfl((int)pk[2 * c2][1], srcA), b1 = (u32)__shfl((int)pk[2 * c2 + 1][1], srcA);
        u32 a2 = (u32)__shfl((int)pk[2 * c2][0], srcB), b2 = (u32)__shfl((int)pk[2 * c2 + 1][0], srcB);
        u32 a3 = (u32)__shfl((int)pk[2 * c2][1], srcB), b3 = (u32)__shfl((int)pk[2 * c2 + 1][1], srcB);
        i32x4 w;
        w.x = (int)(hi ? b0 : a0);
        w.y = (int)(hi ? b1 : a1);
        w.z = (int)(hi ? b2 : a2);
        w.w = (int)(hi ? b3 : a3);
        bf16x8 pf = __builtin_bit_cast(bf16x8, w);
        #pragma unroll
        for (int dt = 0; dt < 4; ++dt) o[t][dt] = MFMA16(vf[c2][dt], pf, o[t][dt]);
      }
    }
  }

  #pragma unroll
  for (int t = 0; t < 4; ++t) {
    float ls = l[t];
    ls += __shfl_xor(ls, 16);
    ls += __shfl_xor(ls, 32);
    float inv = 1.f / ls;
    u16* outp = AO + ((long)(b * Nn + q0w + t * 16 + qlane) * Cc) + h * HDd;
    #pragma unroll
    for (int dt = 0; dt < 4; ++dt) {
      u32 lo = packbf2(o[t][dt][0] * inv, o[t][dt][1] * inv);
      u32 hi2 = packbf2(o[t][dt][2] * inv, o[t][dt][3] * inv);
      uint2 st = {lo, hi2};
      *(uint2*)(outp + dt * 16 + g * 4) = st;
    }
  }
}

// ---------------- CLS-row scores (one block per (b,h), atomic accumulate) ----------------
__global__ __launch_bounds__(256) void k_sco_init(float* __restrict__ sco) {
  int gid = blockIdx.x * 256 + threadIdx.x;
  if (gid < Bb * 511) sco[gid] = 0.f;
}

__global__ __launch_bounds__(256) void k_cls(const u16* __restrict__ Q, const u16* __restrict__ K,
                                             const int* __restrict__ lens, float* __restrict__ scores) {
  int bh = blockIdx.x;  // 0..383
  int b = bh / Hh;
  int t = threadIdx.x;
  int len = lens[b];
  __shared__ float qrow[64];
  __shared__ float red[256];
  const u16* Qb = Q + (long)bh * Nn * HDd;
  const u16* Kb = K + (long)bh * Nn * HDd;
  if (t < 64) qrow[t] = bf2f(Qb[t]);
  __syncthreads();
  const bf16x8* kr0 = (const bf16x8*)(Kb + t * HDd);
  const bf16x8* kr1 = (const bf16x8*)(Kb + (t + 256) * HDd);
  float d0 = 0.f, d1 = 0.f;
  #pragma unroll
  for (int c8 = 0; c8 < 8; ++c8) {
    bf16x8 kv0 = kr0[c8], kv1 = kr1[c8];
    #pragma unroll
    for (int j = 0; j < 8; ++j) {
      float qv = qrow[c8 * 8 + j];
      d0 += qv * bf2f((u16)kv0[j]);
      d1 += qv * bf2f((u16)kv1[j]);
    }
  }
  float l0 = (t < len) ? d0 * SCL : -1e9f;
  float l1 = (t + 256 < len) ? d1 * SCL : -1e9f;
  red[t] = fmaxf(l0, l1);
  __syncthreads();
  for (int ss = 128; ss > 0; ss >>= 1) {
    if (t < ss) red[t] = fmaxf(red[t], red[t + ss]);
    __syncthreads();
  }
  float mx = red[0];
  __syncthreads();
  float e0 = __expf(l0 - mx), e1 = __expf(l1 - mx);
  red[t] = e0 + e1;
  __syncthreads();
  for (int ss = 128; ss > 0; ss >>= 1) {
    if (t < ss) red[t] += red[t + ss];
    __syncthreads();
  }
  float w = (1.f / 12.f) / red[0];
  if (t >= 1) atomicAdd(&scores[b * 511 + (t - 1)], e0 * w);
  atomicAdd(&scores[b * 511 + (t + 255)], e1 * w);
}

// ---------------- top-k (bitonic sort 512, desc score / asc idx) ----------------
__device__ __forceinline__ bool sless(float sa, int ia, float sb, int ib) {
  return (sa > sb) || (sa == sb && ia < ib);
}

__global__ __launch_bounds__(256) void k_topk(const float* __restrict__ scores,
                                              const int* __restrict__ lens, float* __restrict__ dout) {
  int b = blockIdx.x, t = threadIdx.x;
  __shared__ float sc[512];
  __shared__ int id[512];
  float ninf = -__builtin_inff();
  int len = lens[b];
  for (int i = t; i < 512; i += 256) {
    sc[i] = (i < 511 && (i + 1) < len) ? scores[b * 511 + i] : ninf;
    id[i] = i;
  }
  for (int k = 2; k <= 512; k <<= 1) {
    for (int j = k >> 1; j > 0; j >>= 1) {
      __syncthreads();
      for (int i = t; i < 512; i += 256) {
        int ixj = i ^ j;
        if (ixj > i) {
          float si = sc[i], sj = sc[ixj];
          int ii = id[i], ij = id[ixj];
          bool up = ((i & k) == 0);
          bool dosw = up ? sless(sj, ij, si, ii) : sless(si, ii, sj, ij);
          if (dosw) {
            sc[i] = sj; sc[ixj] = si;
            id[i] = ij; id[ixj] = ii;
          }
        }
      }
    }
  }
  __syncthreads();
  int left = (int)ceilf((float)(len - 1) * 0.7f);
  const long OFF_IDX = (long)Bb * Nn * Cc + (long)Bb * BND * Cc;
  for (int p = t; p < BND; p += 256) {
    dout[OFF_IDX + (long)b * BND + p] = (p < left) ? (float)id[p] : 1e9f;
  }
  if (b == 0 && t == 0) dout[OFF_IDX + (long)Bb * BND] = (float)BND;
}

__global__ __launch_bounds__(256) void k_bcast(float* __restrict__ dout) {
  long gid = (long)blockIdx.x * 256 + threadIdx.x;
  const long total = (long)Bb * BND * (Cc / 4);
  if (gid >= total) return;
  long bp = gid / (Cc / 4);
  int c4 = (int)(gid % (Cc / 4));
  const long OFF_INDEX = (long)Bb * Nn * Cc;
  const long OFF_IDX = OFF_INDEX + (long)Bb * BND * Cc;
  float v = dout[OFF_IDX + bp];
  float4 f = {v, v, v, v};
  *(float4*)&dout[OFF_INDEX + bp * Cc + (long)c4 * 4] = f;
}

// ---------------- launch ----------------
extern "C" void kernel_launch(void* const* d_in, const int* in_sizes, int n_in,
                              void* d_out, int out_size, void* d_ws, size_t ws_size,
                              hipStream_t stream) {
  const float* x = (const float*)d_in[0];
  const int* mask = (const int*)d_in[1];
  const float* wqkv = (const float*)d_in[2];
  const float* wproj = (const float*)d_in[3];
  const float* bproj = (const float*)d_in[4];
  float* out = (float*)d_out;

  char* ws = (char*)d_ws;
  u16* Qw  = (u16*)(ws);                    // 25165824 B
  u16* Kw  = (u16*)(ws + 25165824L);        // 25165824 B
  u16* Vtw = (u16*)(ws + 50331648L);        // 25165824 B
  u16* XB  = (u16*)(ws + 75497472L);        // 25165824 B (x bf16; reused as attn out)
  u16* AO  = XB;
  u16* WQT = (u16*)(ws + 100663296L);       // 3538944 B
  u16* WPT = (u16*)(ws + 104202240L);       // 1179648 B
  float* SCO = (float*)(ws + 105381888L);   // 65536 B
  int* LEN = (int*)(ws + 105447424L);       // 128 B

  k_convx<<<12288, 256, 0, stream>>>(x, XB);
  k_transpose<<<dim3(72, 24), 256, 0, stream>>>(wqkv, WQT, 768, 2304);
  k_transpose<<<dim3(24, 24), 256, 0, stream>>>(wproj, WPT, 768, 768);
  k_lens<<<32, 256, 0, stream>>>(mask, LEN);
  k_sco_init<<<64, 256, 0, stream>>>(SCO);
  // QKV GEMM: Q/K blocks (n<1536, swapped operands) and V blocks (n>=1536)
  k_gemm2<0, 1><<<dim3(128, 12), 256, 0, stream>>>(XB, WQT, 0, Qw, Kw, nullptr, nullptr, nullptr);
  k_gemm2<0, 0><<<dim3(128, 6), 256, 0, stream>>>(XB, WQT, 1536, nullptr, nullptr, Vtw, nullptr, nullptr);
  k_attn<<<768, 256, 0, stream>>>(Qw, Kw, Vtw, LEN, AO);
  k_gemm2<1, 0><<<dim3(128, 6), 256, 0, stream>>>(AO, WPT, 0, nullptr, nullptr, nullptr, out, bproj);
  k_cls<<<384, 256, 0, stream>>>(Qw, Kw, LEN, SCO);
  k_topk<<<32, 256, 0, stream>>>(SCO, LEN, out);
  k_bcast<<<8592, 256, 0, stream>>>(out);
}